// Round 8
// baseline (867.903 us; speedup 1.0000x reference)
//
#include <hip/hip_runtime.h>

namespace {

typedef float v4f __attribute__((ext_vector_type(4)));

constexpr int   kB     = 32768;
constexpr int   kT     = 50;
constexpr float kDT    = 0.01f;
constexpr float kGamma = 0.1f;
constexpr float kSigma = 0.2f;
constexpr float kTau   = 0.5f;

// Packed-weight image (float offsets), in exact consumption order.
constexpr int WS_L1Z = 0;              // 10 rows x [b, w_t, w_x0..15, pad2] = 20
constexpr int WS_L1P = 200;            // 10 x 20
constexpr int WS_L2Z = 400;            // 10 x [b, w0..9, pad] = 12
constexpr int WS_L2P = 520;            // 10 x 12
constexpr int WS_L3Z = 640;            // 16 x 12
constexpr int WS_L3P = 832;            // 8 x 12
constexpr int WS_UPD = 928;            // 16 x [Arow16 Brow8 Crow16 Drow8 Acol16 Ccol16] = 80
constexpr int WS_DH  = 2208;           // 8 x [Bcol16 Dcol16] = 32   (end 2464)

__device__ __forceinline__ float ftanh(float x) {
  float e = exp2f(x * 2.8853900817779268f);   // exp(2x) via exp2
  return 1.0f - 2.0f * __builtin_amdgcn_rcpf(e + 1.0f);
}

// ---------------- prep: pack weights into one shared stream -----------------
__global__ __launch_bounds__(256) void prep_kernel(
    const float* __restrict__ A,   const float* __restrict__ Bm,
    const float* __restrict__ Cm,  const float* __restrict__ Dm,
    const float* __restrict__ pW1, const float* __restrict__ pb1,
    const float* __restrict__ pW2, const float* __restrict__ pb2,
    const float* __restrict__ pW3, const float* __restrict__ pb3,
    const float* __restrict__ zW1, const float* __restrict__ zb1,
    const float* __restrict__ zW2, const float* __restrict__ zb2,
    const float* __restrict__ zW3, const float* __restrict__ zb3,
    float* __restrict__ ws, float* __restrict__ out)
{
  const int tid = threadIdx.x;
  if (tid < 2) out[tid] = 0.0f;   // harness re-poisons out each replay
  // L1 (z then phi): row = [bias, w_t, w_x0..w_x15, pad, pad]
  for (int c = tid; c < 20; c += 256) {
    int m = c / 10, row = c % 10;
    const float* W = m ? pW1 : zW1;
    const float* b = m ? pb1 : zb1;
    float* d = ws + WS_L1Z + c * 20;
    d[0] = b[row];
    for (int k = 0; k < 17; ++k) d[1 + k] = W[k * 10 + row];
    d[18] = 0.f; d[19] = 0.f;
  }
  // L2 (z then phi)
  for (int c = tid; c < 20; c += 256) {
    int m = c / 10, row = c % 10;
    const float* W = m ? pW2 : zW2;
    const float* b = m ? pb2 : zb2;
    float* d = ws + WS_L2Z + c * 12;
    d[0] = b[row];
    for (int k = 0; k < 10; ++k) d[1 + k] = W[k * 10 + row];
    d[11] = 0.f;
  }
  // L3: 16 zv rows then 8 u rows
  for (int c = tid; c < 24; c += 256) {
    float* d = ws + WS_L3Z + c * 12;
    if (c < 16) {
      d[0] = zb3[c];
      for (int k = 0; k < 10; ++k) d[1 + k] = zW3[k * 16 + c];
    } else {
      int row = c - 16;
      d[0] = pb3[row];
      for (int k = 0; k < 10; ++k) d[1 + k] = pW3[k * 8 + row];
    }
    d[11] = 0.f;
  }
  // UPD row i: A row, B row, C row, D row, A col, C col
  for (int i = tid; i < 16; i += 256) {
    float* d = ws + WS_UPD + i * 80;
    for (int j = 0; j < 16; ++j) d[j]      = A [i * 16 + j];
    for (int j = 0; j < 8;  ++j) d[16 + j] = Bm[i * 8  + j];
    for (int j = 0; j < 16; ++j) d[24 + j] = Cm[i * 16 + j];
    for (int j = 0; j < 8;  ++j) d[40 + j] = Dm[i * 8  + j];
    for (int j = 0; j < 16; ++j) d[48 + j] = A [j * 16 + i];
    for (int j = 0; j < 16; ++j) d[64 + j] = Cm[j * 16 + i];
  }
  // DH row i: B col, D col
  for (int i = tid; i < 8; i += 256) {
    float* d = ws + WS_DH + i * 32;
    for (int j = 0; j < 16; ++j) d[j]      = Bm[j * 8 + i];
    for (int j = 0; j < 16; ++j) d[16 + j] = Dm[j * 8 + i];
  }
}

// -------- main: pure thread-per-element. Zero LDS, zero barriers. -----------
// 512 waves (half the SIMDs idle by design) but each wave's critical path is
// only its own elements' math: all weights wave-uniform via s_load streams,
// every MAC is v_fmac(v, s, v). launch_bounds(64,1) -> 1 wave/EU VGPR budget
// so the ~88-float live set stays architecturally resident.
__global__ __launch_bounds__(64, 1) void bsde_kernel(
    const float* __restrict__ dw,  const float* __restrict__ X0,
    const float* __restrict__ yW1, const float* __restrict__ yb1,
    const float* __restrict__ yW2, const float* __restrict__ yb2,
    const float* __restrict__ yW3, const float* __restrict__ yb3,
    const float* __restrict__ ws,  float* __restrict__ out)
{
  const int lane = threadIdx.x;
  const int e    = blockIdx.x * 64 + lane;

  // ---- X0 load (b128) + Y0 MLP (one-time, original layout) ----
  v4f x4[4], y4[4];
#pragma unroll
  for (int c = 0; c < 4; ++c) x4[c] = *(const v4f*)&X0[e * 16 + 4 * c];

  {
    float h1t[10], h2t[10];
#pragma unroll
    for (int r = 0; r < 10; ++r) {
      float s = yb1[r];
#pragma unroll
      for (int c = 0; c < 4; ++c)
#pragma unroll
        for (int j = 0; j < 4; ++j) s += x4[c][j] * yW1[(4 * c + j) * 10 + r];
      h1t[r] = ftanh(s);
    }
#pragma unroll
    for (int r = 0; r < 10; ++r) {
      float s = yb2[r];
#pragma unroll
      for (int k = 0; k < 10; ++k) s += h1t[k] * yW2[k * 10 + r];
      h2t[r] = ftanh(s);
    }
#pragma unroll
    for (int r = 0; r < 16; ++r) {
      float s = yb3[r];
#pragma unroll
      for (int k = 0; k < 10; ++k) s += h2t[k] * yW3[k * 16 + r];
      y4[r >> 2][r & 3] = s;
    }
  }

  float lcp = 0.0f;
  float dwv = dw[e];   // t=0 increment

  // ------------------------------- time loop -------------------------------
#pragma unroll 1
  for (int t = 0; t < kT; ++t) {
    float dwn = (t < kT - 1) ? dw[(t + 1) * kB + e] : 0.0f;
    const float tv = (float)t * kDT;
    const float wt = (t == 0 || t == kT - 1) ? 1.0f : 2.0f;

    // L1: z rows then phi rows (weights streamed in this exact order)
    float hz[10], hp[10];
#pragma unroll
    for (int r = 0; r < 10; ++r) {
      const float* w = ws + WS_L1Z + r * 20;
      float s = w[0] + tv * w[1];
#pragma unroll
      for (int c = 0; c < 4; ++c)
#pragma unroll
        for (int j = 0; j < 4; ++j) s += x4[c][j] * w[2 + 4 * c + j];
      hz[r] = ftanh(s);
    }
#pragma unroll
    for (int r = 0; r < 10; ++r) {
      const float* w = ws + WS_L1P + r * 20;
      float s = w[0] + tv * w[1];
#pragma unroll
      for (int c = 0; c < 4; ++c)
#pragma unroll
        for (int j = 0; j < 4; ++j) s += x4[c][j] * w[2 + 4 * c + j];
      hp[r] = ftanh(s);
    }

    // L2
    float gz[10], gp[10];
#pragma unroll
    for (int r = 0; r < 10; ++r) {
      const float* w = ws + WS_L2Z + r * 12;
      float s = w[0];
#pragma unroll
      for (int k = 0; k < 10; ++k) s += hz[k] * w[1 + k];
      gz[r] = ftanh(s);
    }
#pragma unroll
    for (int r = 0; r < 10; ++r) {
      const float* w = ws + WS_L2P + r * 12;
      float s = w[0];
#pragma unroll
      for (int k = 0; k < 10; ++k) s += hp[k] * w[1 + k];
      gp[r] = ftanh(s);
    }

    // L3: 16 Zv rows, 8 u rows
    v4f zv4[4], u2[2];
#pragma unroll
    for (int r = 0; r < 16; ++r) {
      const float* w = ws + WS_L3Z + r * 12;
      float s = w[0];
#pragma unroll
      for (int k = 0; k < 10; ++k) s += gz[k] * w[1 + k];
      zv4[r >> 2][r & 3] = s;
    }
#pragma unroll
    for (int r = 0; r < 8; ++r) {
      const float* w = ws + WS_L3P + r * 12;
      float s = w[0];
#pragma unroll
      for (int k = 0; k < 10; ++k) s += gp[k] * w[1 + k];
      u2[r >> 2][r & 3] = s;
    }

    // UPD: all 16 state rows
    v4f Xn[4], Yn[4];
#pragma unroll
    for (int r = 0; r < 16; ++r) {
      const float* w = ws + WS_UPD + r * 80;
      float dx = kGamma, fx = kSigma;
#pragma unroll
      for (int c = 0; c < 4; ++c)
#pragma unroll
        for (int j = 0; j < 4; ++j) {
          dx += w[4 * c + j]      * x4[c][j];
          fx += w[24 + 4 * c + j] * x4[c][j];
        }
#pragma unroll
      for (int c = 0; c < 2; ++c)
#pragma unroll
        for (int j = 0; j < 4; ++j) {
          dx += w[16 + 4 * c + j] * u2[c][j];
          fx += w[40 + 4 * c + j] * u2[c][j];
        }
      const float xi = x4[r >> 2][r & 3];
      const float yi = y4[r >> 2][r & 3];
      const float zi = zv4[r >> 2][r & 3];
      float dy = xi;
#pragma unroll
      for (int c = 0; c < 4; ++c)
#pragma unroll
        for (int j = 0; j < 4; ++j)
          dy += w[48 + 4 * c + j] * y4[c][j] + w[64 + 4 * c + j] * zv4[c][j];
      Xn[r >> 2][r & 3] = xi + kDT * dx + dwv * fx;
      Yn[r >> 2][r & 3] = yi - kDT * dy + dwv * zi;
    }

    // dH: all 8 control rows
    float s2 = 0.0f;
#pragma unroll
    for (int r = 0; r < 8; ++r) {
      const float* w = ws + WS_DH + r * 32;
      float dh = u2[r >> 2][r & 3];
#pragma unroll
      for (int c = 0; c < 4; ++c)
#pragma unroll
        for (int j = 0; j < 4; ++j)
          dh += w[4 * c + j] * y4[c][j] + w[16 + 4 * c + j] * zv4[c][j];
      s2 += dh * dh;
    }
    lcp += (0.5f * kDT * kTau * kTau) * wt * s2;

#pragma unroll
    for (int c = 0; c < 4; ++c) { x4[c] = Xn[c]; y4[c] = Yn[c]; }
    dwv = dwn;
  }

  // ---- losses ----
  float bp = 0.0f;
#pragma unroll
  for (int c = 0; c < 4; ++c)
#pragma unroll
    for (int j = 0; j < 4; ++j) {
      float d = y4[c][j] - x4[c][j];
      bp += d * d;
    }

#pragma unroll
  for (int s = 32; s > 0; s >>= 1) {
    bp  += __shfl_down(bp,  s, 64);
    lcp += __shfl_down(lcp, s, 64);
  }
  if (lane == 0) {
    atomicAdd(&out[0], bp  * (1.0f / (float)kB));
    atomicAdd(&out[1], lcp * (1.0f / (float)kB));
  }
}

} // namespace

extern "C" void kernel_launch(void* const* d_in, const int* in_sizes, int n_in,
                              void* d_out, int out_size, void* d_ws, size_t ws_size,
                              hipStream_t stream) {
  (void)in_sizes; (void)n_in; (void)ws_size; (void)out_size;

  const float* dw  = (const float*)d_in[0];
  const float* X0  = (const float*)d_in[1];
  const float* A   = (const float*)d_in[2];
  const float* Bm  = (const float*)d_in[3];
  const float* Cm  = (const float*)d_in[4];
  const float* Dm  = (const float*)d_in[5];
  const float* pW1 = (const float*)d_in[6];
  const float* pb1 = (const float*)d_in[7];
  const float* pW2 = (const float*)d_in[8];
  const float* pb2 = (const float*)d_in[9];
  const float* pW3 = (const float*)d_in[10];
  const float* pb3 = (const float*)d_in[11];
  const float* zW1 = (const float*)d_in[12];
  const float* zb1 = (const float*)d_in[13];
  const float* zW2 = (const float*)d_in[14];
  const float* zb2 = (const float*)d_in[15];
  const float* zW3 = (const float*)d_in[16];
  const float* zb3 = (const float*)d_in[17];
  const float* yW1 = (const float*)d_in[18];
  const float* yb1 = (const float*)d_in[19];
  const float* yW2 = (const float*)d_in[20];
  const float* yb2 = (const float*)d_in[21];
  const float* yW3 = (const float*)d_in[22];
  const float* yb3 = (const float*)d_in[23];
  float* out = (float*)d_out;
  float* ws  = (float*)d_ws;

  prep_kernel<<<1, 256, 0, stream>>>(
      A, Bm, Cm, Dm,
      pW1, pb1, pW2, pb2, pW3, pb3,
      zW1, zb1, zW2, zb2, zW3, zb3, ws, out);

  bsde_kernel<<<kB / 64, 64, 0, stream>>>(
      dw, X0, yW1, yb1, yW2, yb2, yW3, yb3, ws, out);
}

// Round 9
// 371.164 us; speedup vs baseline: 2.3383x; 2.3383x over previous
//
#include <hip/hip_runtime.h>

namespace {

typedef float v4f __attribute__((ext_vector_type(4)));
typedef float v2f __attribute__((ext_vector_type(2)));

constexpr int   kB     = 32768;
constexpr int   kT     = 50;
constexpr float kDT    = 0.01f;
constexpr float kGamma = 0.1f;
constexpr float kSigma = 0.2f;
constexpr float kTau   = 0.5f;

// Weight image (dword offsets), sub-lane-major, consumed from LDS.
constexpr int WT_L1  = 0;      // 4 subs x 5 rows x 20: [b, w_t, 0, 0, wx0..15]
constexpr int WT_L2  = 400;    // 4 x 5 x 12:  [b, w0..9, pad]
constexpr int WT_L3Z = 640;    // 4 x 4 x 12:  zv row 4s+r
constexpr int WT_L3P = 832;    // 4 x 2 x 12:  u  row 2s+r
constexpr int WT_UPD = 928;    // 4 x 4 x 80:  state row 4s+r: Arow BrowCrow Drow Acol Ccol
constexpr int WT_DH  = 2208;   // 4 x 2 x 32:  ctrl row 2s+r: Bcol Dcol
constexpr int WT_SZ  = 2464;   // 9856 B

__device__ __forceinline__ float ftanh(float x) {
  float e = exp2f(x * 2.8853900817779268f);   // exp(2x) via exp2
  return 1.0f - 2.0f * __builtin_amdgcn_rcpf(e + 1.0f);
}

// ---------------- prep: pack weights into the sub-lane-major image ----------
__global__ __launch_bounds__(256) void prep_kernel(
    const float* __restrict__ A,   const float* __restrict__ Bm,
    const float* __restrict__ Cm,  const float* __restrict__ Dm,
    const float* __restrict__ pW1, const float* __restrict__ pb1,
    const float* __restrict__ pW2, const float* __restrict__ pb2,
    const float* __restrict__ pW3, const float* __restrict__ pb3,
    const float* __restrict__ zW1, const float* __restrict__ zb1,
    const float* __restrict__ zW2, const float* __restrict__ zb2,
    const float* __restrict__ zW3, const float* __restrict__ zb3,
    float* __restrict__ ws, float* __restrict__ out)
{
  const int tid = threadIdx.x;
  if (tid < 2) out[tid] = 0.0f;   // harness re-poisons out each replay
  // L1: sub s -> MLP m=s>>1 (0=z,1=phi), rows (s&1)*5 .. +5
  for (int c = tid; c < 20; c += 256) {
    int s = c / 5, r = c % 5;
    int m = s >> 1, row = (s & 1) * 5 + r;
    const float* W = m ? pW1 : zW1;
    const float* b = m ? pb1 : zb1;
    float* d = ws + WT_L1 + s * 100 + r * 20;
    d[0] = b[row]; d[1] = W[row]; d[2] = 0.f; d[3] = 0.f;
    for (int j = 0; j < 16; ++j) d[4 + j] = W[(j + 1) * 10 + row];
  }
  // L2
  for (int c = tid; c < 20; c += 256) {
    int s = c / 5, r = c % 5;
    int m = s >> 1, row = (s & 1) * 5 + r;
    const float* W = m ? pW2 : zW2;
    const float* b = m ? pb2 : zb2;
    float* d = ws + WT_L2 + s * 60 + r * 12;
    d[0] = b[row];
    for (int k = 0; k < 10; ++k) d[1 + k] = W[k * 10 + row];
    d[11] = 0.f;
  }
  // L3 zv: sub s -> rows 4s..4s+3 (z-MLP output, width 16)
  for (int i = tid; i < 16; i += 256) {
    int s = i >> 2, r = i & 3;
    float* d = ws + WT_L3Z + s * 48 + r * 12;
    d[0] = zb3[i];
    for (int k = 0; k < 10; ++k) d[1 + k] = zW3[k * 16 + i];
    d[11] = 0.f;
  }
  // L3 u: sub s -> rows 2s, 2s+1 (phi output, width 8)
  for (int i = tid; i < 8; i += 256) {
    int s = i >> 1, r = i & 1;
    float* d = ws + WT_L3P + s * 24 + r * 12;
    d[0] = pb3[i];
    for (int k = 0; k < 10; ++k) d[1 + k] = pW3[k * 8 + i];
    d[11] = 0.f;
  }
  // UPD: sub s -> state rows 4s..4s+3
  for (int i = tid; i < 16; i += 256) {
    int s = i >> 2, r = i & 3;
    float* d = ws + WT_UPD + s * 320 + r * 80;
    for (int j = 0; j < 16; ++j) d[j]      = A [i * 16 + j];
    for (int j = 0; j < 8;  ++j) d[16 + j] = Bm[i * 8  + j];
    for (int j = 0; j < 16; ++j) d[24 + j] = Cm[i * 16 + j];
    for (int j = 0; j < 8;  ++j) d[40 + j] = Dm[i * 8  + j];
    for (int j = 0; j < 16; ++j) d[48 + j] = A [j * 16 + i];
    for (int j = 0; j < 16; ++j) d[64 + j] = Cm[j * 16 + i];
  }
  // DH: sub s -> control rows 2s, 2s+1
  for (int i = tid; i < 8; i += 256) {
    int s = i >> 1, r = i & 1;
    float* d = ws + WT_DH + s * 64 + r * 32;
    for (int j = 0; j < 16; ++j) d[j]      = Bm[j * 8 + i];
    for (int j = 0; j < 16; ++j) d[16 + j] = Dm[j * 8 + i];
  }
}

// b + sum_{k<10} h[k] * w[1+k], w = LDS row [b, w0..9, pad], 16B-aligned
__device__ __forceinline__ float dot10(const float* wlds, const float h[10]) {
  v4f a  = *(const v4f*)(wlds);
  v4f b4 = *(const v4f*)(wlds + 4);
  v4f c4 = *(const v4f*)(wlds + 8);
  float s = a[0];
  s += h[0] * a[1] + h[1] * a[2] + h[2] * a[3];
  s += h[3] * b4[0] + h[4] * b4[1] + h[5] * b4[2] + h[6] * b4[3];
  s += h[7] * c4[0] + h[8] * c4[1] + h[9] * c4[2];
  return s;
}

#define WAVE_FENCE() asm volatile("" ::: "memory")

// -------- main: quarter-wave split, barrier-free wave-synchronous LDS -------
// 1 wave/block, 16 elements/wave, 4 sub-lanes/element. 2048 blocks -> 8/CU,
// 2 waves/SIMD. All cross-sub exchange via same-wave LDS (in-order pipe, no
// __syncthreads). Code is branch-free: sub enters addresses only.
__global__ __launch_bounds__(64, 2) void bsde_kernel(
    const float* __restrict__ dw,  const float* __restrict__ X0,
    const float* __restrict__ yW1, const float* __restrict__ yb1,
    const float* __restrict__ yW2, const float* __restrict__ yb2,
    const float* __restrict__ yW3, const float* __restrict__ yb3,
    const float* __restrict__ ws,  float* __restrict__ out)
{
  __shared__ __align__(16) float WT[WT_SZ];
  __shared__ __align__(16) float XY[16][36];  // X 0..15, Y 16..31
  __shared__ __align__(16) float EH[16][28];  // h: z 0..9 @0, phi 0..9 @12
  __shared__ __align__(16) float EG[16][28];  // g: same layout
  __shared__ __align__(16) float ZU[16][28];  // zv 0..15, u 16..23

  const int lane = threadIdx.x;       // 0..63
  const int ei   = lane & 15;         // element in block
  const int sub  = lane >> 4;         // 0..3 (likely = HW phase group)
  const int e    = blockIdx.x * 16 + ei;
  const int m    = sub >> 1;          // 0=z-MLP, 1=phi-MLP
  const int half = sub & 1;

  // One-time: stage weight image into LDS (wave-private block, no barrier).
  for (int i = lane; i < WT_SZ; i += 64) WT[i] = ws[i];
  WAVE_FENCE();

  const float* wl1 = WT + WT_L1  + sub * 100;
  const float* wl2 = WT + WT_L2  + sub * 60;
  const float* wlz = WT + WT_L3Z + sub * 48;
  const float* wlu = WT + WT_L3P + sub * 24;
  const float* wup = WT + WT_UPD + sub * 320;
  const float* wdh = WT + WT_DH  + sub * 64;

  // ---- X0 + Y0 MLP (one-time, every lane full, bit-identical across subs) --
  v4f x4[4], y4[4];
#pragma unroll
  for (int c = 0; c < 4; ++c) x4[c] = *(const v4f*)&X0[e * 16 + 4 * c];
  {
    float h1t[10], h2t[10];
#pragma unroll
    for (int r = 0; r < 10; ++r) {
      float s = yb1[r];
#pragma unroll
      for (int c = 0; c < 4; ++c)
#pragma unroll
        for (int j = 0; j < 4; ++j) s += x4[c][j] * yW1[(4 * c + j) * 10 + r];
      h1t[r] = ftanh(s);
    }
#pragma unroll
    for (int r = 0; r < 10; ++r) {
      float s = yb2[r];
#pragma unroll
      for (int k = 0; k < 10; ++k) s += h1t[k] * yW2[k * 10 + r];
      h2t[r] = ftanh(s);
    }
#pragma unroll
    for (int r = 0; r < 16; ++r) {
      float s = yb3[r];
#pragma unroll
      for (int k = 0; k < 10; ++k) s += h2t[k] * yW3[k * 16 + r];
      y4[r >> 2][r & 3] = s;
    }
  }
  // Seed XY (one sub writes; values identical across subs). One-time diverge.
  if (sub == 0) {
#pragma unroll
    for (int c = 0; c < 4; ++c) {
      *(v4f*)&XY[ei][4 * c]      = x4[c];
      *(v4f*)&XY[ei][16 + 4 * c] = y4[c];
    }
  }
  WAVE_FENCE();

  float lcp = 0.0f;
  float dwv = dw[e];
  v4f Xn = {0.f, 0.f, 0.f, 0.f}, Yn = Xn;

  // ------------------------------- time loop -------------------------------
#pragma unroll 1
  for (int t = 0; t < kT; ++t) {
    float dwn = (t < kT - 1) ? dw[(t + 1) * kB + e] : 0.0f;
    const float tv = (float)t * kDT;
    const float wt = (t == 0 || t == kT - 1) ? 1.0f : 2.0f;

    // Full state + own chunks (runtime sub -> LDS address, never reg index)
#pragma unroll
    for (int c = 0; c < 4; ++c) {
      x4[c] = *(const v4f*)&XY[ei][4 * c];
      y4[c] = *(const v4f*)&XY[ei][16 + 4 * c];
    }
    v4f xo = *(const v4f*)&XY[ei][4 * sub];
    v4f yo = *(const v4f*)&XY[ei][16 + 4 * sub];
    asm volatile("" : "+v"(x4[0]), "+v"(x4[1]), "+v"(x4[2]), "+v"(x4[3]),
                      "+v"(y4[0]), "+v"(y4[1]), "+v"(y4[2]), "+v"(y4[3]));

    // L1: own 5 rows of own MLP
    float h_own[5];
#pragma unroll
    for (int r = 0; r < 5; ++r) {
      const float* w = wl1 + r * 20;
      v4f w0 = *(const v4f*)w;
      float s = w0[0] + tv * w0[1];
#pragma unroll
      for (int c = 0; c < 4; ++c) {
        v4f wx = *(const v4f*)(w + 4 + 4 * c);
#pragma unroll
        for (int j = 0; j < 4; ++j) s += x4[c][j] * wx[j];
      }
      h_own[r] = ftanh(s);
    }
#pragma unroll
    for (int r = 0; r < 5; ++r) EH[ei][m * 12 + half * 5 + r] = h_own[r];
    WAVE_FENCE();
    float hh[10];
    {
      v4f a = *(const v4f*)&EH[ei][m * 12];
      v4f b = *(const v4f*)&EH[ei][m * 12 + 4];
      v4f c = *(const v4f*)&EH[ei][m * 12 + 8];
#pragma unroll
      for (int k = 0; k < 4; ++k) hh[k] = a[k];
#pragma unroll
      for (int k = 0; k < 4; ++k) hh[4 + k] = b[k];
      hh[8] = c[0]; hh[9] = c[1];
    }

    // L2: own 5 rows
    float g_own[5];
#pragma unroll
    for (int r = 0; r < 5; ++r) g_own[r] = ftanh(dot10(wl2 + r * 12, hh));
#pragma unroll
    for (int r = 0; r < 5; ++r) EG[ei][m * 12 + half * 5 + r] = g_own[r];
    WAVE_FENCE();
    float gz[10], gp[10];
    {
      v4f a = *(const v4f*)&EG[ei][0], b = *(const v4f*)&EG[ei][4],
          c = *(const v4f*)&EG[ei][8];
      v4f d = *(const v4f*)&EG[ei][12], f = *(const v4f*)&EG[ei][16],
          g = *(const v4f*)&EG[ei][20];
#pragma unroll
      for (int k = 0; k < 4; ++k) { gz[k] = a[k]; gz[4 + k] = b[k]; }
      gz[8] = c[0]; gz[9] = c[1];
#pragma unroll
      for (int k = 0; k < 4; ++k) { gp[k] = d[k]; gp[4 + k] = f[k]; }
      gp[8] = g[0]; gp[9] = g[1];
    }

    // L3: 4 zv rows (4s..4s+3) + 2 u rows (2s,2s+1) per sub — symmetric
    float zq[4], uq[2];
#pragma unroll
    for (int r = 0; r < 4; ++r) zq[r] = dot10(wlz + r * 12, gz);
#pragma unroll
    for (int r = 0; r < 2; ++r) uq[r] = dot10(wlu + r * 12, gp);
    {
      v4f zz = {zq[0], zq[1], zq[2], zq[3]};
      *(v4f*)&ZU[ei][4 * sub] = zz;
      v2f uu = {uq[0], uq[1]};
      *(v2f*)&ZU[ei][16 + 2 * sub] = uu;
    }
    WAVE_FENCE();
    v4f zv4[4], u2[2];
#pragma unroll
    for (int c = 0; c < 4; ++c) zv4[c] = *(const v4f*)&ZU[ei][4 * c];
#pragma unroll
    for (int c = 0; c < 2; ++c) u2[c] = *(const v4f*)&ZU[ei][16 + 4 * c];
    asm volatile("" : "+v"(zv4[0]), "+v"(zv4[1]), "+v"(zv4[2]), "+v"(zv4[3]),
                      "+v"(u2[0]), "+v"(u2[1]));

    // UPD: own 4 state rows
#pragma unroll
    for (int r = 0; r < 4; ++r) {
      const float* w = wup + r * 80;
      float dx = kGamma, fx = kSigma;
#pragma unroll
      for (int c = 0; c < 4; ++c) {
        v4f wa = *(const v4f*)(w + 4 * c);
        v4f wc = *(const v4f*)(w + 24 + 4 * c);
#pragma unroll
        for (int j = 0; j < 4; ++j) {
          dx += wa[j] * x4[c][j];
          fx += wc[j] * x4[c][j];
        }
      }
#pragma unroll
      for (int c = 0; c < 2; ++c) {
        v4f wb = *(const v4f*)(w + 16 + 4 * c);
        v4f wd = *(const v4f*)(w + 40 + 4 * c);
#pragma unroll
        for (int j = 0; j < 4; ++j) {
          dx += wb[j] * u2[c][j];
          fx += wd[j] * u2[c][j];
        }
      }
      float dy = xo[r];
#pragma unroll
      for (int c = 0; c < 4; ++c) {
        v4f wac = *(const v4f*)(w + 48 + 4 * c);
        v4f wcc = *(const v4f*)(w + 64 + 4 * c);
#pragma unroll
        for (int j = 0; j < 4; ++j)
          dy += wac[j] * y4[c][j] + wcc[j] * zv4[c][j];
      }
      Xn[r] = xo[r] + kDT * dx + dwv * fx;
      Yn[r] = yo[r] - kDT * dy + dwv * zq[r];
    }

    // dH: own 2 control rows
    float s2 = 0.0f;
#pragma unroll
    for (int r = 0; r < 2; ++r) {
      const float* w = wdh + r * 32;
      float dh = uq[r];
#pragma unroll
      for (int c = 0; c < 4; ++c) {
        v4f wb = *(const v4f*)(w + 4 * c);
        v4f wd = *(const v4f*)(w + 16 + 4 * c);
#pragma unroll
        for (int j = 0; j < 4; ++j)
          dh += wb[j] * y4[c][j] + wd[j] * zv4[c][j];
      }
      s2 += dh * dh;
    }
    lcp += (0.5f * kDT * kTau * kTau) * wt * s2;

    // Publish own chunks (reads of XY this iter all precede these in order)
    *(v4f*)&XY[ei][4 * sub]      = Xn;
    *(v4f*)&XY[ei][16 + 4 * sub] = Yn;
    dwv = dwn;
    WAVE_FENCE();
  }

  // ---- losses: each lane holds its own 4 final rows ----
  float bp = 0.0f;
#pragma unroll
  for (int r = 0; r < 4; ++r) { float d = Yn[r] - Xn[r]; bp += d * d; }

#pragma unroll
  for (int s = 32; s > 0; s >>= 1) {
    bp  += __shfl_down(bp,  s, 64);
    lcp += __shfl_down(lcp, s, 64);
  }
  if (lane == 0) {
    atomicAdd(&out[0], bp  * (1.0f / (float)kB));
    atomicAdd(&out[1], lcp * (1.0f / (float)kB));
  }
}

} // namespace

extern "C" void kernel_launch(void* const* d_in, const int* in_sizes, int n_in,
                              void* d_out, int out_size, void* d_ws, size_t ws_size,
                              hipStream_t stream) {
  (void)in_sizes; (void)n_in; (void)ws_size; (void)out_size;

  const float* dw  = (const float*)d_in[0];
  const float* X0  = (const float*)d_in[1];
  const float* A   = (const float*)d_in[2];
  const float* Bm  = (const float*)d_in[3];
  const float* Cm  = (const float*)d_in[4];
  const float* Dm  = (const float*)d_in[5];
  const float* pW1 = (const float*)d_in[6];
  const float* pb1 = (const float*)d_in[7];
  const float* pW2 = (const float*)d_in[8];
  const float* pb2 = (const float*)d_in[9];
  const float* pW3 = (const float*)d_in[10];
  const float* pb3 = (const float*)d_in[11];
  const float* zW1 = (const float*)d_in[12];
  const float* zb1 = (const float*)d_in[13];
  const float* zW2 = (const float*)d_in[14];
  const float* zb2 = (const float*)d_in[15];
  const float* zW3 = (const float*)d_in[16];
  const float* zb3 = (const float*)d_in[17];
  const float* yW1 = (const float*)d_in[18];
  const float* yb1 = (const float*)d_in[19];
  const float* yW2 = (const float*)d_in[20];
  const float* yb2 = (const float*)d_in[21];
  const float* yW3 = (const float*)d_in[22];
  const float* yb3 = (const float*)d_in[23];
  float* out = (float*)d_out;
  float* ws  = (float*)d_ws;

  prep_kernel<<<1, 256, 0, stream>>>(
      A, Bm, Cm, Dm,
      pW1, pb1, pW2, pb2, pW3, pb3,
      zW1, zb1, zW2, zb2, zW3, zb3, ws, out);

  bsde_kernel<<<kB / 16, 64, 0, stream>>>(
      dw, X0, yW1, yb1, yW2, yb2, yW3, yb3, ws, out);
}

// Round 10
// 303.017 us; speedup vs baseline: 2.8642x; 1.2249x over previous
//
#include <hip/hip_runtime.h>

namespace {

typedef float v4f __attribute__((ext_vector_type(4)));
typedef float v2f __attribute__((ext_vector_type(2)));

constexpr int   kB     = 32768;
constexpr int   kT     = 50;
constexpr float kDT    = 0.01f;
constexpr float kGamma = 0.1f;
constexpr float kSigma = 0.2f;
constexpr float kTau   = 0.5f;

// Packed-weight workspace layout (float offsets). All v2f reads 8B-aligned.
constexpr int WS_L1  = 0;              // [2 mlps][10 rows][20]  b, w_t, wx0..15, pad2
constexpr int WS_L2  = WS_L1  + 400;   // [2][10][12]            b, 0, w0..9
constexpr int WS_L3  = WS_L2  + 240;   // [24][12] rows: q0 zv0-7, q1 zv8-15, q2 u0-3, q3 u4-7
constexpr int WS_UPD = WS_L3  + 288;   // [16][80]  Arow16 Brow8 Crow16 Drow8 Acol16 Ccol16
constexpr int WS_DH  = WS_UPD + 1280;  // [8][32]   Bcol16 Dcol16

__device__ __forceinline__ float ftanh(float x) {
  float e = exp2f(x * 2.8853900817779268f);   // exp(2x) via exp2
  return 1.0f - 2.0f * __builtin_amdgcn_rcpf(e + 1.0f);
}

__device__ __forceinline__ v2f lo2(v4f a) { return __builtin_shufflevector(a, a, 0, 1); }
__device__ __forceinline__ v2f hi2(v4f a) { return __builtin_shufflevector(a, a, 2, 3); }

// ---------------- prep: pack weights in per-wave consumption order ----------
__global__ __launch_bounds__(256) void prep_kernel(
    const float* __restrict__ A,   const float* __restrict__ Bm,
    const float* __restrict__ Cm,  const float* __restrict__ Dm,
    const float* __restrict__ pW1, const float* __restrict__ pb1,
    const float* __restrict__ pW2, const float* __restrict__ pb2,
    const float* __restrict__ pW3, const float* __restrict__ pb3,
    const float* __restrict__ zW1, const float* __restrict__ zb1,
    const float* __restrict__ zW2, const float* __restrict__ zb2,
    const float* __restrict__ zW3, const float* __restrict__ zb3,
    float* __restrict__ ws, float* __restrict__ out)
{
  const int tid = threadIdx.x;
  if (tid < 2) out[tid] = 0.0f;   // harness re-poisons out each replay
  // L1: m=0 -> z rows 0..9 ; m=1 -> phi rows 0..9
  for (int c = tid; c < 20; c += 256) {
    int m = c / 10, row = c % 10;
    const float* W = m ? pW1 : zW1;
    const float* b = m ? pb1 : zb1;
    float* d = ws + WS_L1 + c * 20;
    d[0] = b[row];
    for (int k = 0; k < 17; ++k) d[1 + k] = W[k * 10 + row];
    d[18] = 0.f; d[19] = 0.f;
  }
  // L2: [b, 0, w0..9]
  for (int c = tid; c < 20; c += 256) {
    int m = c / 10, row = c % 10;
    const float* W = m ? pW2 : zW2;
    const float* b = m ? pb2 : zb2;
    float* d = ws + WS_L2 + c * 12;
    d[0] = b[row]; d[1] = 0.f;
    for (int k = 0; k < 10; ++k) d[2 + k] = W[k * 10 + row];
  }
  // L3: [b, 0, w0..9]; rows 0..15 zv, 16..23 u
  for (int c = tid; c < 24; c += 256) {
    float* d = ws + WS_L3 + c * 12;
    d[1] = 0.f;
    if (c < 16) {
      d[0] = zb3[c];
      for (int k = 0; k < 10; ++k) d[2 + k] = zW3[k * 16 + c];
    } else {
      int row = c - 16;
      d[0] = pb3[row];
      for (int k = 0; k < 10; ++k) d[2 + k] = pW3[k * 8 + row];
    }
  }
  // UPD: per state row i: A row, B row, C row, D row, A col, C col
  for (int i = tid; i < 16; i += 256) {
    float* d = ws + WS_UPD + i * 80;
    for (int j = 0; j < 16; ++j) d[j]      = A [i * 16 + j];
    for (int j = 0; j < 8;  ++j) d[16 + j] = Bm[i * 8  + j];
    for (int j = 0; j < 16; ++j) d[24 + j] = Cm[i * 16 + j];
    for (int j = 0; j < 8;  ++j) d[40 + j] = Dm[i * 8  + j];
    for (int j = 0; j < 16; ++j) d[48 + j] = A [j * 16 + i];
    for (int j = 0; j < 16; ++j) d[64 + j] = Cm[j * 16 + i];
  }
  // DH: per control row i: B col, D col
  for (int i = tid; i < 8; i += 256) {
    float* d = ws + WS_DH + i * 32;
    for (int j = 0; j < 16; ++j) d[j]      = Bm[j * 8 + i];
    for (int j = 0; j < 16; ++j) d[16 + j] = Dm[j * 8 + i];
  }
}

// Wave-specialized UPD + dH, packed-fp32 (v2f -> v_pk_fma_f32).
template <int Q>
__device__ __forceinline__ void upd_body(
    const float* __restrict__ Wup, const float* __restrict__ Wdh,
    const v4f x4[4], const v4f y4[4], const v4f zvf[4], const v4f uff[2],
    float dwv, float* __restrict__ Xn, float* __restrict__ Yn, float& s2)
{
  v2f x2[8], y2[8], z2[8], u2[4];
#pragma unroll
  for (int c = 0; c < 4; ++c) {
    x2[2 * c] = lo2(x4[c]);  x2[2 * c + 1] = hi2(x4[c]);
    y2[2 * c] = lo2(y4[c]);  y2[2 * c + 1] = hi2(y4[c]);
    z2[2 * c] = lo2(zvf[c]); z2[2 * c + 1] = hi2(zvf[c]);
  }
#pragma unroll
  for (int c = 0; c < 2; ++c) { u2[2 * c] = lo2(uff[c]); u2[2 * c + 1] = hi2(uff[c]); }

#pragma unroll
  for (int r = 0; r < 4; ++r) {
    const float* w = Wup + r * 80;        // state row i = 4Q + r
    v2f dx = {kGamma, 0.f}, fx = {kSigma, 0.f};
#pragma unroll
    for (int c = 0; c < 8; ++c) {
      dx += *(const v2f*)(w + 2 * c)      * x2[c];
      fx += *(const v2f*)(w + 24 + 2 * c) * x2[c];
    }
#pragma unroll
    for (int c = 0; c < 4; ++c) {
      dx += *(const v2f*)(w + 16 + 2 * c) * u2[c];
      fx += *(const v2f*)(w + 40 + 2 * c) * u2[c];
    }
    const float xi = x4[Q][r];
    const float yi = y4[Q][r];
    const float zi = zvf[Q][r];
    v2f dy = {xi, 0.f};
#pragma unroll
    for (int c = 0; c < 8; ++c)
      dy += *(const v2f*)(w + 48 + 2 * c) * y2[c] + *(const v2f*)(w + 64 + 2 * c) * z2[c];
    Xn[r] = xi + kDT * (dx[0] + dx[1]) + dwv * (fx[0] + fx[1]);
    Yn[r] = yi - kDT * (dy[0] + dy[1]) + dwv * zi;
  }
#pragma unroll
  for (int r = 0; r < 2; ++r) {
    const int i = 2 * Q + r;
    const float* w = Wdh + i * 32;
    v2f dh = {uff[i >> 2][i & 3], 0.f};
#pragma unroll
    for (int c = 0; c < 8; ++c)
      dh += *(const v2f*)(w + 2 * c) * y2[c] + *(const v2f*)(w + 16 + 2 * c) * z2[c];
    const float d = dh[0] + dh[1];
    s2 += d * d;
  }
}

// ---------------- main: 4 waves / 64 elements, 2 barriers per step ----------
// R5 structure (waves 0,1 redundant z L1+L2; waves 2,3 phi) + packed fp32.
__global__ __launch_bounds__(256, 2) void bsde_kernel(
    const float* __restrict__ dw,  const float* __restrict__ X0,
    const float* __restrict__ yW1, const float* __restrict__ yb1,
    const float* __restrict__ yW2, const float* __restrict__ yb2,
    const float* __restrict__ yW3, const float* __restrict__ yb3,
    const float* __restrict__ ws,  float* __restrict__ out)
{
  __shared__ float XYt[64][36];   // dwords 0..15 = X, 16..31 = Y
  __shared__ float ZUt[64][28];   // 0..15 = Zv, 16..23 = u

  const int lane = threadIdx.x & 63;
  const int q    = __builtin_amdgcn_readfirstlane((int)(threadIdx.x >> 6));
  const int e    = blockIdx.x * 64 + lane;

  const int m      = q >> 1;                                   // 0=z, 1=phi
  const int l3off  = (q & 2) ? (192 + (q & 1) * 48) : (q * 96);
  const float* Wl1 = ws + WS_L1  + m * 200;
  const float* Wl2 = ws + WS_L2  + m * 120;
  const float* Wl3 = ws + WS_L3  + l3off;
  const float* Wup = ws + WS_UPD + q * 320;
  const float* Wdh = ws + WS_DH;

  // ---- X0 load (b128) + Y0 MLP (redundant per wave, one-time) ----
  v4f x4[4], y4[4];
#pragma unroll
  for (int c = 0; c < 4; ++c) x4[c] = *(const v4f*)&X0[e * 16 + 4 * c];

  {
    float h1t[10], h2t[10];
#pragma unroll
    for (int r = 0; r < 10; ++r) {
      float s = yb1[r];
#pragma unroll
      for (int c = 0; c < 4; ++c)
#pragma unroll
        for (int j = 0; j < 4; ++j) s += x4[c][j] * yW1[(4 * c + j) * 10 + r];
      h1t[r] = ftanh(s);
    }
#pragma unroll
    for (int r = 0; r < 10; ++r) {
      float s = yb2[r];
#pragma unroll
      for (int k = 0; k < 10; ++k) s += h1t[k] * yW2[k * 10 + r];
      h2t[r] = ftanh(s);
    }
#pragma unroll
    for (int r = 0; r < 16; ++r) {
      float s = yb3[r];
#pragma unroll
      for (int k = 0; k < 10; ++k) s += h2t[k] * yW3[k * 16 + r];
      y4[r >> 2][r & 3] = s;
    }
  }

  // Seed XYt (wave 0 only; values bit-identical across waves), then barrier.
  if (q == 0) {
#pragma unroll
    for (int c = 0; c < 4; ++c) {
      *(v4f*)&XYt[lane][4 * c]      = x4[c];
      *(v4f*)&XYt[lane][16 + 4 * c] = y4[c];
    }
  }
  __syncthreads();

  float lcp = 0.0f;
  float Xn[4], Yn[4];
  float dwv = dw[e];   // t=0 increment

  // ------------------------------- time loop -------------------------------
#pragma unroll 1
  for (int t = 0; t < kT; ++t) {
    float dwn = (t < kT - 1) ? dw[(t + 1) * kB + e] : 0.0f;
    const float tv = (float)t * kDT;
    const float wt = (t == 0 || t == kT - 1) ? 1.0f : 2.0f;

    // Read full state (b128), pin in registers.
#pragma unroll
    for (int c = 0; c < 4; ++c) {
      x4[c] = *(const v4f*)&XYt[lane][4 * c];
      y4[c] = *(const v4f*)&XYt[lane][16 + 4 * c];
    }
    asm volatile("" : "+v"(x4[0]), "+v"(x4[1]), "+v"(x4[2]), "+v"(x4[3]),
                      "+v"(y4[0]), "+v"(y4[1]), "+v"(y4[2]), "+v"(y4[3]));

    v2f xp[8];
#pragma unroll
    for (int c = 0; c < 4; ++c) { xp[2 * c] = lo2(x4[c]); xp[2 * c + 1] = hi2(x4[c]); }

    // L1: full 10 rows of own MLP (packed dots, k=16 -> 8 pk)
    float hh[10];
#pragma unroll
    for (int r = 0; r < 10; ++r) {
      const float* w = Wl1 + r * 20;
      v2f bw = *(const v2f*)w;                 // [bias, w_t]
      v2f acc = {bw[0] + tv * bw[1], 0.f};
#pragma unroll
      for (int c = 0; c < 8; ++c) acc += *(const v2f*)(w + 2 + 2 * c) * xp[c];
      hh[r] = ftanh(acc[0] + acc[1]);
    }
    v2f hp[5];
#pragma unroll
    for (int k = 0; k < 5; ++k) { v2f t2 = {hh[2 * k], hh[2 * k + 1]}; hp[k] = t2; }

    // L2: full 10 rows (5 pk each)
    float gg[10];
#pragma unroll
    for (int r = 0; r < 10; ++r) {
      const float* w = Wl2 + r * 12;
      v2f acc = {w[0], 0.f};
#pragma unroll
      for (int k = 0; k < 5; ++k) acc += *(const v2f*)(w + 2 + 2 * k) * hp[k];
      gg[r] = ftanh(acc[0] + acc[1]);
    }
    v2f gp[5];
#pragma unroll
    for (int k = 0; k < 5; ++k) { v2f t2 = {gg[2 * k], gg[2 * k + 1]}; gp[k] = t2; }

    // L3: z-waves 8 Zv rows each; phi-waves 4 u rows each
    if (q < 2) {
      float z[8];
#pragma unroll
      for (int r = 0; r < 8; ++r) {
        const float* w = Wl3 + r * 12;
        v2f acc = {w[0], 0.f};
#pragma unroll
        for (int k = 0; k < 5; ++k) acc += *(const v2f*)(w + 2 + 2 * k) * gp[k];
        z[r] = acc[0] + acc[1];
      }
      v4f z0 = {z[0], z[1], z[2], z[3]}, z1 = {z[4], z[5], z[6], z[7]};
      *(v4f*)&ZUt[lane][8 * q]     = z0;
      *(v4f*)&ZUt[lane][8 * q + 4] = z1;
    } else {
      float z[4];
#pragma unroll
      for (int r = 0; r < 4; ++r) {
        const float* w = Wl3 + r * 12;
        v2f acc = {w[0], 0.f};
#pragma unroll
        for (int k = 0; k < 5; ++k) acc += *(const v2f*)(w + 2 + 2 * k) * gp[k];
        z[r] = acc[0] + acc[1];
      }
      v4f zz = {z[0], z[1], z[2], z[3]};
      *(v4f*)&ZUt[lane][16 + 4 * (q - 2)] = zz;
    }
    __syncthreads();                       // B1: ZU visible

    v4f zvf[4], uff[2];
#pragma unroll
    for (int c = 0; c < 4; ++c) zvf[c] = *(const v4f*)&ZUt[lane][4 * c];
#pragma unroll
    for (int c = 0; c < 2; ++c) uff[c] = *(const v4f*)&ZUt[lane][16 + 4 * c];
    asm volatile("" : "+v"(zvf[0]), "+v"(zvf[1]), "+v"(zvf[2]), "+v"(zvf[3]),
                      "+v"(uff[0]), "+v"(uff[1]));

    // UPD + dH, wave-specialized (uniform branch)
    float s2 = 0.0f;
    if      (q == 0) upd_body<0>(Wup, Wdh, x4, y4, zvf, uff, dwv, Xn, Yn, s2);
    else if (q == 1) upd_body<1>(Wup, Wdh, x4, y4, zvf, uff, dwv, Xn, Yn, s2);
    else if (q == 2) upd_body<2>(Wup, Wdh, x4, y4, zvf, uff, dwv, Xn, Yn, s2);
    else             upd_body<3>(Wup, Wdh, x4, y4, zvf, uff, dwv, Xn, Yn, s2);
    lcp += (0.5f * kDT * kTau * kTau) * wt * s2;

    // Publish own rows (b128)
    {
      v4f xs = {Xn[0], Xn[1], Xn[2], Xn[3]};
      v4f ys = {Yn[0], Yn[1], Yn[2], Yn[3]};
      *(v4f*)&XYt[lane][4 * q]      = xs;
      *(v4f*)&XYt[lane][16 + 4 * q] = ys;
    }
    dwv = dwn;
    __syncthreads();                       // B2: XY visible
  }

  // ---- losses ----
#pragma unroll
  for (int c = 0; c < 4; ++c) {
    x4[c] = *(const v4f*)&XYt[lane][4 * c];
    y4[c] = *(const v4f*)&XYt[lane][16 + 4 * c];
  }
  float bp = 0.0f;
  if (q == 0) {
#pragma unroll
    for (int c = 0; c < 4; ++c)
#pragma unroll
      for (int j = 0; j < 4; ++j) {
        float d = y4[c][j] - x4[c][j];
        bp += d * d;
      }
  }
#pragma unroll
  for (int s = 32; s > 0; s >>= 1) {
    bp  += __shfl_down(bp,  s, 64);
    lcp += __shfl_down(lcp, s, 64);
  }
  if (lane == 0) {
    if (q == 0) atomicAdd(&out[0], bp * (1.0f / (float)kB));
    atomicAdd(&out[1], lcp * (1.0f / (float)kB));
  }
}

} // namespace

extern "C" void kernel_launch(void* const* d_in, const int* in_sizes, int n_in,
                              void* d_out, int out_size, void* d_ws, size_t ws_size,
                              hipStream_t stream) {
  (void)in_sizes; (void)n_in; (void)ws_size; (void)out_size;

  const float* dw  = (const float*)d_in[0];
  const float* X0  = (const float*)d_in[1];
  const float* A   = (const float*)d_in[2];
  const float* Bm  = (const float*)d_in[3];
  const float* Cm  = (const float*)d_in[4];
  const float* Dm  = (const float*)d_in[5];
  const float* pW1 = (const float*)d_in[6];
  const float* pb1 = (const float*)d_in[7];
  const float* pW2 = (const float*)d_in[8];
  const float* pb2 = (const float*)d_in[9];
  const float* pW3 = (const float*)d_in[10];
  const float* pb3 = (const float*)d_in[11];
  const float* zW1 = (const float*)d_in[12];
  const float* zb1 = (const float*)d_in[13];
  const float* zW2 = (const float*)d_in[14];
  const float* zb2 = (const float*)d_in[15];
  const float* zW3 = (const float*)d_in[16];
  const float* zb3 = (const float*)d_in[17];
  const float* yW1 = (const float*)d_in[18];
  const float* yb1 = (const float*)d_in[19];
  const float* yW2 = (const float*)d_in[20];
  const float* yb2 = (const float*)d_in[21];
  const float* yW3 = (const float*)d_in[22];
  const float* yb3 = (const float*)d_in[23];
  float* out = (float*)d_out;
  float* ws  = (float*)d_ws;

  prep_kernel<<<1, 256, 0, stream>>>(
      A, Bm, Cm, Dm,
      pW1, pb1, pW2, pb2, pW3, pb3,
      zW1, zb1, zW2, zb2, zW3, zb3, ws, out);

  bsde_kernel<<<kB / 64, 256, 0, stream>>>(
      dw, X0, yW1, yb1, yW2, yb2, yW3, yb3, ws, out);
}